// Round 1
// baseline (167.360 us; speedup 1.0000x reference)
//
#include <hip/hip_runtime.h>
#include <hip/hip_bf16.h>

// KANLayer: out = x @ Wb^T + silu(x) @ sum_g(Ws)^T
// Strategy: pack into ONE bf16 GEMM with K=2048:
//   A' = [x | silu(x)]  (8192 x 2048, bf16)
//   W' = [Wb | sum_g Ws] (1024 x 2048, bf16)
//   out = A' @ W'^T  (fp32 accumulate via mfma_f32_16x16x32_bf16)

#define BATCH 8192
#define IN_F 1024
#define OUT_F 1024
#define KP 2048  // packed K = 2*IN_F

typedef unsigned short ushort_t;
typedef __attribute__((ext_vector_type(8))) short short8;
typedef __attribute__((ext_vector_type(4))) float f32x4;

__device__ __forceinline__ ushort_t f2bf(float f) {
  union { float f; unsigned int u; } v;
  v.f = f;
  unsigned int u = v.u;
  u += 0x7fffu + ((u >> 16) & 1u);  // round-to-nearest-even
  return (ushort_t)(u >> 16);
}

__device__ __forceinline__ void async16(const ushort_t* g, ushort_t* l) {
  __builtin_amdgcn_global_load_lds(
      (const __attribute__((address_space(1))) void*)g,
      (__attribute__((address_space(3))) void*)l, 16, 0, 0);
}

// Build A' = [x | silu(x)] as bf16. One thread handles 4 consecutive fp32 of x,
// writes 4 bf16 into each half of the packed row.
__global__ void prep_x(const float* __restrict__ x, ushort_t* __restrict__ Apack) {
  const int idx = blockIdx.x * 256 + threadIdx.x;  // 0 .. 2M-1
  const int b = idx >> 8;                          // row (256 float4 per row)
  const int i = (idx & 255) << 2;                  // col within IN_F
  const float4 xv = *(const float4*)(x + ((size_t)b << 10) + i);

  ushort4 vb;
  vb.x = f2bf(xv.x); vb.y = f2bf(xv.y); vb.z = f2bf(xv.z); vb.w = f2bf(xv.w);

  const float sx = xv.x / (1.0f + __expf(-xv.x));
  const float sy = xv.y / (1.0f + __expf(-xv.y));
  const float sz = xv.z / (1.0f + __expf(-xv.z));
  const float sw = xv.w / (1.0f + __expf(-xv.w));
  ushort4 vs;
  vs.x = f2bf(sx); vs.y = f2bf(sy); vs.z = f2bf(sz); vs.w = f2bf(sw);

  ushort_t* row = Apack + ((size_t)b << 11);  // packed row stride KP=2048
  *(ushort4*)(row + i) = vb;
  *(ushort4*)(row + IN_F + i) = vs;
}

// Build W' = [Wb | sum_g Ws] as bf16 [OUT_F][KP].
__global__ void prep_w(const float* __restrict__ Wb, const float* __restrict__ Ws,
                       ushort_t* __restrict__ Wpack) {
  const int idx = blockIdx.x * 256 + threadIdx.x;  // 0 .. 2M-1
  const int o = idx >> 11;
  const int k = idx & 2047;
  float v;
  if (k < IN_F) {
    v = Wb[((size_t)o << 10) + k];
  } else {
    const float4* p = (const float4*)(Ws + ((((size_t)o << 10) + (size_t)(k - IN_F)) << 3));
    const float4 a = p[0];
    const float4 b = p[1];
    v = ((a.x + a.y) + (a.z + a.w)) + ((b.x + b.y) + (b.z + b.w));
  }
  Wpack[idx] = f2bf(v);
}

// m97-style bf16 GEMM: C[M][N] = A[M][K] @ W[N][K]^T, fp32 out.
// 128x128 tile, BK=32, 256 threads = 4 waves, each wave 64x64 (4x4 MFMA frags).
__global__ __launch_bounds__(256) void gemm_packed(
    const ushort_t* __restrict__ A,  // [BATCH][KP] bf16
    const ushort_t* __restrict__ W,  // [OUT_F][KP] bf16
    float* __restrict__ C) {         // [BATCH][OUT_F] fp32
  __shared__ ushort_t As[128 * 32];
  __shared__ ushort_t Bs[128 * 32];

  const int t = threadIdx.x;
  const int bx = blockIdx.x;  // N tile (OUT_F/128 = 8)
  const int by = blockIdx.y;  // M tile (BATCH/128 = 64)

  const int lane = t & 63;
  const int wave = t >> 6;
  const int wr = wave >> 1;  // wave row 0..1
  const int wc = wave & 1;   // wave col 0..1

  // Staging: 256 threads x 16B = 4 KB/round; tile = 128 rows x 64 B = 8 KB -> 2 rounds.
  // LDS dest must be linear in thread id (wave-uniform base + lane*16).
  const int srow = t >> 2;         // 0..63
  const int scol = (t & 3) << 3;   // bf16 elem offset 0,8,16,24
  const size_t a_g0 = ((size_t)(by * 128 + srow)) * KP + scol;
  const size_t b_g0 = ((size_t)(bx * 128 + srow)) * KP + scol;
  ushort_t* as_d = As + t * 8;
  ushort_t* bs_d = Bs + t * 8;

  f32x4 acc[4][4];
#pragma unroll
  for (int mi = 0; mi < 4; ++mi)
#pragma unroll
    for (int ni = 0; ni < 4; ++ni) acc[mi][ni] = (f32x4){0.f, 0.f, 0.f, 0.f};

  const int arow = wr * 64 + (lane & 15);  // + mi*16
  const int brow = wc * 64 + (lane & 15);  // + ni*16
  const int kofs = (lane >> 4) << 3;       // k offset 0,8,16,24

  for (int k0 = 0; k0 < KP; k0 += 32) {
    __syncthreads();  // previous compute done before overwrite
    async16(A + a_g0 + k0, as_d);
    async16(A + a_g0 + k0 + (size_t)64 * KP, as_d + 2048);
    async16(W + b_g0 + k0, bs_d);
    async16(W + b_g0 + k0 + (size_t)64 * KP, bs_d + 2048);
    __syncthreads();  // compiler drains vmcnt before s_barrier -> LDS ready

    short8 af[4], bfr[4];
#pragma unroll
    for (int mi = 0; mi < 4; ++mi)
      af[mi] = *(const short8*)(As + (arow + mi * 16) * 32 + kofs);
#pragma unroll
    for (int ni = 0; ni < 4; ++ni)
      bfr[ni] = *(const short8*)(Bs + (brow + ni * 16) * 32 + kofs);

#pragma unroll
    for (int mi = 0; mi < 4; ++mi)
#pragma unroll
      for (int ni = 0; ni < 4; ++ni)
        acc[mi][ni] = __builtin_amdgcn_mfma_f32_16x16x32_bf16(af[mi], bfr[ni], acc[mi][ni], 0, 0, 0);
  }

  // Epilogue: C/D layout col=lane&15, row=(lane>>4)*4+reg
  const int col0 = bx * 128 + wc * 64 + (lane & 15);
  const int row0 = by * 128 + wr * 64 + ((lane >> 4) << 2);
#pragma unroll
  for (int mi = 0; mi < 4; ++mi)
#pragma unroll
    for (int ni = 0; ni < 4; ++ni) {
      float* cp = C + (size_t)(row0 + mi * 16) * OUT_F + col0 + ni * 16;
#pragma unroll
      for (int r = 0; r < 4; ++r) cp[(size_t)r * OUT_F] = acc[mi][ni][r];
    }
}

extern "C" void kernel_launch(void* const* d_in, const int* in_sizes, int n_in,
                              void* d_out, int out_size, void* d_ws, size_t ws_size,
                              hipStream_t stream) {
  const float* x = (const float*)d_in[0];
  const float* wb = (const float*)d_in[1];
  const float* ws = (const float*)d_in[2];
  float* out = (float*)d_out;

  ushort_t* Apack = (ushort_t*)d_ws;  // 8192*2048*2 = 33.5 MB
  ushort_t* Wpack = (ushort_t*)((char*)d_ws + (size_t)BATCH * KP * sizeof(ushort_t));  // +4 MB

  prep_x<<<(BATCH * IN_F / 4) / 256, 256, 0, stream>>>(x, Apack);
  prep_w<<<(OUT_F * KP) / 256, 256, 0, stream>>>(wb, ws, Wpack);
  gemm_packed<<<dim3(OUT_F / 128, BATCH / 128), 256, 0, stream>>>(Apack, Wpack, out);
}

// Round 2
// 161.713 us; speedup vs baseline: 1.0349x; 1.0349x over previous
//
#include <hip/hip_runtime.h>
#include <hip/hip_bf16.h>

// KANLayer: out = x @ Wb^T + silu(x) @ sum_g(Ws)^T
// One packed bf16 GEMM, K=2048: A'=[x|silu(x)], W'=[Wb|sum_g Ws], out=A'@W'^T.
// R2: XCD-aware block swizzle in GEMM (kill 3.5x A over-fetch), merged prep kernel.

#define BATCH 8192
#define IN_F 1024
#define OUT_F 1024
#define KP 2048

typedef unsigned short ushort_t;
typedef __attribute__((ext_vector_type(8))) short short8;
typedef __attribute__((ext_vector_type(4))) float f32x4;

__device__ __forceinline__ ushort_t f2bf(float f) {
  union { float f; unsigned int u; } v;
  v.f = f;
  unsigned int u = v.u;
  u += 0x7fffu + ((u >> 16) & 1u);  // RNE
  return (ushort_t)(u >> 16);
}

__device__ __forceinline__ void async16(const ushort_t* g, ushort_t* l) {
  __builtin_amdgcn_global_load_lds(
      (const __attribute__((address_space(1))) void*)g,
      (__attribute__((address_space(3))) void*)l, 16, 0, 0);
}

// ---------------- merged prep ----------------
// blocks [0,4096):        A' = [bf16(x) | bf16(silu(x))], 8 floats/thread
// blocks [4096,5120):     spline half of W': sum_g Ws -> bf16, 4 outputs/thread
// blocks [5120,6144):     base half of W': bf16(Wb), 4 outputs/thread
#define PREP_A_BLOCKS 4096
#define PREP_S_BLOCKS 1024
#define PREP_B_BLOCKS 1024
#define PREP_BLOCKS (PREP_A_BLOCKS + PREP_S_BLOCKS + PREP_B_BLOCKS)

__global__ __launch_bounds__(256) void prep_all(
    const float* __restrict__ x, const float* __restrict__ Wb,
    const float* __restrict__ Ws, ushort_t* __restrict__ Apack,
    ushort_t* __restrict__ Wpack) {
  const int blk = blockIdx.x;
  const int t = threadIdx.x;

  if (blk < PREP_A_BLOCKS) {
    // x -> A' : 1M threads, 8 consecutive floats each
    const int idx = blk * 256 + t;          // [0, 1M)
    const int b = idx >> 7;                 // row, 128 threads/row
    const int i = (idx & 127) << 3;         // col base
    const float4 x0 = *(const float4*)(x + ((size_t)b << 10) + i);
    const float4 x1 = *(const float4*)(x + ((size_t)b << 10) + i + 4);
    float xv[8] = {x0.x, x0.y, x0.z, x0.w, x1.x, x1.y, x1.z, x1.w};
    ushort_t vb[8], vs[8];
#pragma unroll
    for (int j = 0; j < 8; ++j) {
      vb[j] = f2bf(xv[j]);
      vs[j] = f2bf(xv[j] / (1.0f + __expf(-xv[j])));
    }
    ushort_t* row = Apack + ((size_t)b << 11);
    *(short8*)(row + i) = *(short8*)vb;
    *(short8*)(row + IN_F + i) = *(short8*)vs;
  } else if (blk < PREP_A_BLOCKS + PREP_S_BLOCKS) {
    // sum_g Ws -> spline half of W' : 256K threads, 4 (o,i) pairs each
    const int idx = (blk - PREP_A_BLOCKS) * 256 + t;  // [0, 256K)
    const int o = idx >> 8;
    const int i0 = (idx & 255) << 2;
    ushort_t vs[4];
#pragma unroll
    for (int j = 0; j < 4; ++j) {
      const float4* p = (const float4*)(Ws + ((((size_t)o << 10) + i0 + j) << 3));
      const float4 a = p[0];
      const float4 b = p[1];
      vs[j] = f2bf(((a.x + a.y) + (a.z + a.w)) + ((b.x + b.y) + (b.z + b.w)));
    }
    *(ushort4*)(Wpack + ((size_t)o << 11) + IN_F + i0) = *(ushort4*)vs;
  } else {
    // Wb -> base half of W' : 256K threads, 4 elems each
    const int idx = (blk - PREP_A_BLOCKS - PREP_S_BLOCKS) * 256 + t;  // [0, 256K)
    const int o = idx >> 8;
    const int c = (idx & 255) << 2;
    const float4 w = *(const float4*)(Wb + ((size_t)o << 10) + c);
    ushort4 v;
    v.x = f2bf(w.x); v.y = f2bf(w.y); v.z = f2bf(w.z); v.w = f2bf(w.w);
    *(ushort4*)(Wpack + ((size_t)o << 11) + c) = v;
  }
}

// ---------------- GEMM ----------------
// C[M][N] = A[M][K] @ W[N][K]^T, 128x128 tile, BK=32, 4 waves, 4x4 16x16x32 frags.
// XCD swizzle: flat%8 = XCD (round-robin dispatch). Give XCD k M-tiles
// [8k,8k+8) x all 8 N-tiles: per-XCD L2 working set = 4MB A-slab + 4MB W.
__global__ __launch_bounds__(256) void gemm_packed(
    const ushort_t* __restrict__ A,  // [BATCH][KP]
    const ushort_t* __restrict__ W,  // [OUT_F][KP]
    float* __restrict__ C) {         // [BATCH][OUT_F]
  __shared__ ushort_t As[128 * 32];
  __shared__ ushort_t Bs[128 * 32];

  const int t = threadIdx.x;
  const int flat = blockIdx.y * 8 + blockIdx.x;  // grid (8,64), x fastest
  const int xcd = flat & 7;
  const int local = flat >> 3;     // 0..63
  const int nt = local >> 3;       // N-tile 0..7
  const int mt = xcd * 8 + (local & 7);  // M-tile 0..63

  const int lane = t & 63;
  const int wave = t >> 6;
  const int wr = wave >> 1;
  const int wc = wave & 1;

  const int srow = t >> 2;
  const int scol = (t & 3) << 3;
  const size_t a_g0 = ((size_t)(mt * 128 + srow)) * KP + scol;
  const size_t b_g0 = ((size_t)(nt * 128 + srow)) * KP + scol;
  ushort_t* as_d = As + t * 8;
  ushort_t* bs_d = Bs + t * 8;

  f32x4 acc[4][4];
#pragma unroll
  for (int mi = 0; mi < 4; ++mi)
#pragma unroll
    for (int ni = 0; ni < 4; ++ni) acc[mi][ni] = (f32x4){0.f, 0.f, 0.f, 0.f};

  const int arow = wr * 64 + (lane & 15);
  const int brow = wc * 64 + (lane & 15);
  const int kofs = (lane >> 4) << 3;

  for (int k0 = 0; k0 < KP; k0 += 32) {
    __syncthreads();
    async16(A + a_g0 + k0, as_d);
    async16(A + a_g0 + k0 + (size_t)64 * KP, as_d + 2048);
    async16(W + b_g0 + k0, bs_d);
    async16(W + b_g0 + k0 + (size_t)64 * KP, bs_d + 2048);
    __syncthreads();

    short8 af[4], bfr[4];
#pragma unroll
    for (int mi = 0; mi < 4; ++mi)
      af[mi] = *(const short8*)(As + (arow + mi * 16) * 32 + kofs);
#pragma unroll
    for (int ni = 0; ni < 4; ++ni)
      bfr[ni] = *(const short8*)(Bs + (brow + ni * 16) * 32 + kofs);

#pragma unroll
    for (int mi = 0; mi < 4; ++mi)
#pragma unroll
      for (int ni = 0; ni < 4; ++ni)
        acc[mi][ni] = __builtin_amdgcn_mfma_f32_16x16x32_bf16(af[mi], bfr[ni], acc[mi][ni], 0, 0, 0);
  }

  const int col0 = nt * 128 + wc * 64 + (lane & 15);
  const int row0 = mt * 128 + wr * 64 + ((lane >> 4) << 2);
#pragma unroll
  for (int mi = 0; mi < 4; ++mi)
#pragma unroll
    for (int ni = 0; ni < 4; ++ni) {
      float* cp = C + (size_t)(row0 + mi * 16) * OUT_F + col0 + ni * 16;
#pragma unroll
      for (int r = 0; r < 4; ++r) cp[(size_t)r * OUT_F] = acc[mi][ni][r];
    }
}

extern "C" void kernel_launch(void* const* d_in, const int* in_sizes, int n_in,
                              void* d_out, int out_size, void* d_ws, size_t ws_size,
                              hipStream_t stream) {
  const float* x = (const float*)d_in[0];
  const float* wb = (const float*)d_in[1];
  const float* ws = (const float*)d_in[2];
  float* out = (float*)d_out;

  ushort_t* Apack = (ushort_t*)d_ws;                                    // 33.5 MB
  ushort_t* Wpack = (ushort_t*)((char*)d_ws + (size_t)BATCH * KP * 2);  // +4 MB

  prep_all<<<PREP_BLOCKS, 256, 0, stream>>>(x, wb, ws, Apack, Wpack);
  gemm_packed<<<dim3(OUT_F / 128, BATCH / 128), 256, 0, stream>>>(Apack, Wpack, out);
}

// Round 3
// 160.648 us; speedup vs baseline: 1.0418x; 1.0066x over previous
//
#include <hip/hip_runtime.h>
#include <hip/hip_bf16.h>

// KANLayer: out = x @ Wb^T + silu(x) @ sum_g(Ws)^T
// One packed bf16 GEMM, K=2048: A'=[x|silu(x)], W'=[Wb|sum_g Ws], out=A'@W'^T.
// R3: 128x64 tile -> 1024 blocks (4/CU, was 2/CU grid-limited at 18.7% occ).

#define BATCH 8192
#define IN_F 1024
#define OUT_F 1024
#define KP 2048

typedef unsigned short ushort_t;
typedef __attribute__((ext_vector_type(8))) short short8;
typedef __attribute__((ext_vector_type(4))) float f32x4;

__device__ __forceinline__ ushort_t f2bf(float f) {
  union { float f; unsigned int u; } v;
  v.f = f;
  unsigned int u = v.u;
  u += 0x7fffu + ((u >> 16) & 1u);  // RNE
  return (ushort_t)(u >> 16);
}

__device__ __forceinline__ void async16(const ushort_t* g, ushort_t* l) {
  __builtin_amdgcn_global_load_lds(
      (const __attribute__((address_space(1))) void*)g,
      (__attribute__((address_space(3))) void*)l, 16, 0, 0);
}

// ---------------- merged prep (unchanged from R2: ~traffic floor) -----------
#define PREP_A_BLOCKS 4096
#define PREP_S_BLOCKS 1024
#define PREP_B_BLOCKS 1024
#define PREP_BLOCKS (PREP_A_BLOCKS + PREP_S_BLOCKS + PREP_B_BLOCKS)

__global__ __launch_bounds__(256) void prep_all(
    const float* __restrict__ x, const float* __restrict__ Wb,
    const float* __restrict__ Ws, ushort_t* __restrict__ Apack,
    ushort_t* __restrict__ Wpack) {
  const int blk = blockIdx.x;
  const int t = threadIdx.x;

  if (blk < PREP_A_BLOCKS) {
    const int idx = blk * 256 + t;
    const int b = idx >> 7;
    const int i = (idx & 127) << 3;
    const float4 x0 = *(const float4*)(x + ((size_t)b << 10) + i);
    const float4 x1 = *(const float4*)(x + ((size_t)b << 10) + i + 4);
    float xv[8] = {x0.x, x0.y, x0.z, x0.w, x1.x, x1.y, x1.z, x1.w};
    ushort_t vb[8], vs[8];
#pragma unroll
    for (int j = 0; j < 8; ++j) {
      vb[j] = f2bf(xv[j]);
      vs[j] = f2bf(xv[j] / (1.0f + __expf(-xv[j])));
    }
    ushort_t* row = Apack + ((size_t)b << 11);
    *(short8*)(row + i) = *(short8*)vb;
    *(short8*)(row + IN_F + i) = *(short8*)vs;
  } else if (blk < PREP_A_BLOCKS + PREP_S_BLOCKS) {
    const int idx = (blk - PREP_A_BLOCKS) * 256 + t;
    const int o = idx >> 8;
    const int i0 = (idx & 255) << 2;
    ushort_t vs[4];
#pragma unroll
    for (int j = 0; j < 4; ++j) {
      const float4* p = (const float4*)(Ws + ((((size_t)o << 10) + i0 + j) << 3));
      const float4 a = p[0];
      const float4 b = p[1];
      vs[j] = f2bf(((a.x + a.y) + (a.z + a.w)) + ((b.x + b.y) + (b.z + b.w)));
    }
    *(ushort4*)(Wpack + ((size_t)o << 11) + IN_F + i0) = *(ushort4*)vs;
  } else {
    const int idx = (blk - PREP_A_BLOCKS - PREP_S_BLOCKS) * 256 + t;
    const int o = idx >> 8;
    const int c = (idx & 255) << 2;
    const float4 w = *(const float4*)(Wb + ((size_t)o << 10) + c);
    ushort4 v;
    v.x = f2bf(w.x); v.y = f2bf(w.y); v.z = f2bf(w.z); v.w = f2bf(w.w);
    *(ushort4*)(Wpack + ((size_t)o << 11) + c) = v;
  }
}

// ---------------- GEMM ----------------
// C[M][N] = A[M][K] @ W[N][K]^T. Tile 128M x 64N, BK=32, 256 thr = 4 waves,
// wave tile 64x32 (4x2 frags of 16x16x32). Grid (16,64) = 1024 blocks = 4/CU.
// XCD swizzle: xcd = flat%8 owns M-tiles [8k,8k+8), sweeps 16 N-tiles fastest
// (A M-tile 512KB stays hot in its L2; W read once from HBM, L3-shared).
__global__ __launch_bounds__(256) void gemm_packed(
    const ushort_t* __restrict__ A,  // [BATCH][KP]
    const ushort_t* __restrict__ W,  // [OUT_F][KP]
    float* __restrict__ C) {         // [BATCH][OUT_F]
  __shared__ ushort_t As[128 * 32];  // 8 KB
  __shared__ ushort_t Bs[64 * 32];   // 4 KB

  const int t = threadIdx.x;
  const int flat = blockIdx.y * 16 + blockIdx.x;
  const int xcd = flat & 7;
  const int local = flat >> 3;            // 0..127
  const int nt = local & 15;              // N-tile 0..15 (fastest within XCD)
  const int mt = xcd * 8 + (local >> 4);  // M-tile 0..63

  const int lane = t & 63;
  const int wave = t >> 6;
  const int wr = wave >> 1;  // M half (64 rows)
  const int wc = wave & 1;   // N half (32 cols)

  const int srow = t >> 2;         // 0..63
  const int scol = (t & 3) << 3;
  const size_t a_g0 = ((size_t)(mt * 128 + srow)) * KP + scol;
  const size_t b_g0 = ((size_t)(nt * 64 + srow)) * KP + scol;
  ushort_t* as_d = As + t * 8;
  ushort_t* bs_d = Bs + t * 8;

  f32x4 acc[4][2];
#pragma unroll
  for (int mi = 0; mi < 4; ++mi)
#pragma unroll
    for (int ni = 0; ni < 2; ++ni) acc[mi][ni] = (f32x4){0.f, 0.f, 0.f, 0.f};

  const int arow = wr * 64 + (lane & 15);
  const int brow = wc * 32 + (lane & 15);
  const int kofs = (lane >> 4) << 3;

  for (int k0 = 0; k0 < KP; k0 += 32) {
    __syncthreads();
    async16(A + a_g0 + k0, as_d);
    async16(A + a_g0 + k0 + (size_t)64 * KP, as_d + 2048);
    async16(W + b_g0 + k0, bs_d);
    __syncthreads();

    short8 af[4], bfr[2];
#pragma unroll
    for (int mi = 0; mi < 4; ++mi)
      af[mi] = *(const short8*)(As + (arow + mi * 16) * 32 + kofs);
#pragma unroll
    for (int ni = 0; ni < 2; ++ni)
      bfr[ni] = *(const short8*)(Bs + (brow + ni * 16) * 32 + kofs);

#pragma unroll
    for (int mi = 0; mi < 4; ++mi)
#pragma unroll
      for (int ni = 0; ni < 2; ++ni)
        acc[mi][ni] = __builtin_amdgcn_mfma_f32_16x16x32_bf16(af[mi], bfr[ni], acc[mi][ni], 0, 0, 0);
  }

  const int col0 = nt * 64 + wc * 32 + (lane & 15);
  const int row0 = mt * 128 + wr * 64 + ((lane >> 4) << 2);
#pragma unroll
  for (int mi = 0; mi < 4; ++mi)
#pragma unroll
    for (int ni = 0; ni < 2; ++ni) {
      float* cp = C + (size_t)(row0 + mi * 16) * OUT_F + col0 + ni * 16;
#pragma unroll
      for (int r = 0; r < 4; ++r) cp[(size_t)r * OUT_F] = acc[mi][ni][r];
    }
}

extern "C" void kernel_launch(void* const* d_in, const int* in_sizes, int n_in,
                              void* d_out, int out_size, void* d_ws, size_t ws_size,
                              hipStream_t stream) {
  const float* x = (const float*)d_in[0];
  const float* wb = (const float*)d_in[1];
  const float* ws = (const float*)d_in[2];
  float* out = (float*)d_out;

  ushort_t* Apack = (ushort_t*)d_ws;                                    // 33.5 MB
  ushort_t* Wpack = (ushort_t*)((char*)d_ws + (size_t)BATCH * KP * 2);  // +4 MB

  prep_all<<<PREP_BLOCKS, 256, 0, stream>>>(x, wb, ws, Apack, Wpack);
  gemm_packed<<<dim3(OUT_F / 64, BATCH / 128), 256, 0, stream>>>(Apack, Wpack, out);
}